// Round 1
// baseline (3686.972 us; speedup 1.0000x reference)
//
#include <hip/hip_runtime.h>
#include <hip/hip_fp16.h>

// 2-layer LSTM, B=256 T=512 I=32 H=256.
// Design: 8 batch-groups x 32 batches; 16 wgs/group; each wg owns 16 L0-units +
// 16 L1-units, weights register-resident as fp16 MFMA B-fragments. Per phase p:
// L0 step p and L1 step p-1 (both consume h0[p-1]); h exchanged via global fp16
// double buffers; custom agent-scope flag barrier per batch-group.

#define GROUPS 8
#define WPG    16
#define NTH    512
#define QB     32
#define HH     256
#define TT     512
#define II     32

typedef _Float16 f16x8 __attribute__((ext_vector_type(8)));
typedef float    f32x4 __attribute__((ext_vector_type(4)));

__device__ __forceinline__ f16x8 cvt8(const float* p) {
  const float4 a = *(const float4*)p;
  const float4 b = *(const float4*)(p + 4);
  f16x8 r;
  r[0]=(_Float16)a.x; r[1]=(_Float16)a.y; r[2]=(_Float16)a.z; r[3]=(_Float16)a.w;
  r[4]=(_Float16)b.x; r[5]=(_Float16)b.y; r[6]=(_Float16)b.z; r[7]=(_Float16)b.w;
  return r;
}

__device__ __forceinline__ float sigm(float x){ return 1.f/(1.f + __expf(-x)); }
__device__ __forceinline__ float tanh_(float x){ return 1.f - 2.f/(1.f + __expf(2.f*x)); }

__global__ void zero_ws(uint4* p, int n) {
  int i = blockIdx.x * blockDim.x + threadIdx.x;
  if (i < n) p[i] = make_uint4(0u,0u,0u,0u);
}

__global__ __launch_bounds__(NTH, 2) void lstm_kernel(
    const float* __restrict__ M,
    const float* __restrict__ Wih0, const float* __restrict__ Whh0,
    const float* __restrict__ bih0, const float* __restrict__ bhh0,
    const float* __restrict__ Wih1, const float* __restrict__ Whh1,
    const float* __restrict__ bih1, const float* __restrict__ bhh1,
    float* __restrict__ out, char* __restrict__ ws)
{
  __shared__ float Gbuf[QB * 129];              // gate pre-activations [32][128], pad->129
  __shared__ __align__(16) char h0l[QB * 512];  // h0[p-1] staged, fp16, XOR-swizzled
  __shared__ __align__(16) char h1l[QB * 512];  // h1[p-2] staged

  const int tid  = threadIdx.x;
  const int lane = tid & 63;
  const int wv   = tid >> 6;           // 0..7
  const int g    = blockIdx.x & 7;     // batch group (XCD locality heuristic)
  const int w    = blockIdx.x >> 3;    // 0..15 wg within group

  char* h0g = ws;                      // 2 parities x [256][256] fp16 = 262144 B
  char* h1g = ws + 262144;
  unsigned* flags = (unsigned*)(ws + 524288);   // [8][16] monotone phase counters

  const int col16 = lane & 15;
  const int ko8   = (lane >> 4) << 3;  // k-offset in elements (0,8,16,24)
  const int q     = wv & 3;            // gate: 0=i 1=f 2=g 3=o
  const bool isL1 = wv >= 4;
  const int grow  = q * HH + w * 16 + col16;    // global weight row (gate col)

  // ---- weight fragments -> registers (loaded once) ----
  const float* WA = isL1 ? Wih1 : Whh0;
  f16x8 BA[8], BB[8], Bi0;
  #pragma unroll
  for (int kt = 0; kt < 8; ++kt)
    BA[kt] = cvt8(WA + (size_t)grow * HH + kt * 32 + ko8);
  if (isL1) {
    #pragma unroll
    for (int kt = 0; kt < 8; ++kt)
      BB[kt] = cvt8(Whh1 + (size_t)grow * HH + kt * 32 + ko8);
  } else {
    Bi0 = cvt8(Wih0 + grow * II + ko8);
  }
  const float bias = isL1 ? (bih1[grow] + bhh1[grow]) : (bih0[grow] + bhh0[grow]);

  // elementwise ownership: thread -> (batch, unit); c-state lives in registers
  const int eb = tid & 31;
  const int eu = tid >> 5;             // 0..15
  float c0 = 0.f, c1 = 0.f;

  for (int p = 0; p <= TT; ++p) {
    const int rdpar = (p + 1) & 1;
    const int wrpar = p & 1;

    // ---- stage h0[p-1], h1[p-2] into LDS (16B chunks, XOR swizzle) ----
    {
      const char* s0 = h0g + rdpar * 131072;
      const char* s1 = h1g + rdpar * 131072;
      #pragma unroll
      for (int pass = 0; pass < 4; ++pass) {
        int c   = tid + pass * NTH;          // 0..2047
        int bi  = c >> 10;                   // 0: h0, 1: h1
        int cc  = c & 1023;
        int row = cc >> 5, ci = cc & 31;
        const uint4 v = *(const uint4*)((bi ? s1 : s0) +
                          (((g * QB + row) << 9) + (ci << 4)));
        *(uint4*)((bi ? h1l : h0l) +
                  ((row << 9) + ((ci << 4) ^ ((row & 7) << 4)))) = v;
      }
    }
    __syncthreads();

    // ---- MFMA: gates[32 x 16cols] for this wave's gate-column slice ----
    {
      f32x4 a0 = {bias, bias, bias, bias};
      f32x4 a1 = a0;
      const bool active = isL1 ? (p >= 1) : (p < TT);
      if (active) {
        if (!isL1) {
          const float* m0 = M + (((size_t)(g*QB + col16     ) * TT + p) * II + ko8);
          const float* m1 = M + (((size_t)(g*QB + 16 + col16) * TT + p) * II + ko8);
          f16x8 am0 = cvt8(m0), am1 = cvt8(m1);
          a0 = __builtin_amdgcn_mfma_f32_16x16x32_f16(am0, Bi0, a0, 0, 0, 0);
          a1 = __builtin_amdgcn_mfma_f32_16x16x32_f16(am1, Bi0, a1, 0, 0, 0);
        }
        #pragma unroll
        for (int kt = 0; kt < 8; ++kt) {
          int r0 = col16, r1 = 16 + col16;
          int kb = (kt << 6) + ((lane >> 4) << 4);
          f16x8 x0 = *(const f16x8*)(h0l + ((r0 << 9) + (kb ^ ((r0 & 7) << 4))));
          f16x8 x1 = *(const f16x8*)(h0l + ((r1 << 9) + (kb ^ ((r1 & 7) << 4))));
          a0 = __builtin_amdgcn_mfma_f32_16x16x32_f16(x0, BA[kt], a0, 0, 0, 0);
          a1 = __builtin_amdgcn_mfma_f32_16x16x32_f16(x1, BA[kt], a1, 0, 0, 0);
        }
        if (isL1) {
          #pragma unroll
          for (int kt = 0; kt < 8; ++kt) {
            int r0 = col16, r1 = 16 + col16;
            int kb = (kt << 6) + ((lane >> 4) << 4);
            f16x8 y0 = *(const f16x8*)(h1l + ((r0 << 9) + (kb ^ ((r0 & 7) << 4))));
            f16x8 y1 = *(const f16x8*)(h1l + ((r1 << 9) + (kb ^ ((r1 & 7) << 4))));
            a0 = __builtin_amdgcn_mfma_f32_16x16x32_f16(y0, BB[kt], a0, 0, 0, 0);
            a1 = __builtin_amdgcn_mfma_f32_16x16x32_f16(y1, BB[kt], a1, 0, 0, 0);
          }
        }
      }
      const int colL = (wv << 4) + col16;
      const int r0 = (lane >> 4) << 2;
      #pragma unroll
      for (int r = 0; r < 4; ++r) {
        Gbuf[(r0 + r) * 129 + colL]      = a0[r];
        Gbuf[(r0 + r + 16) * 129 + colL] = a1[r];
      }
    }
    __syncthreads();

    // ---- elementwise gate nonlinearity + state update ----
    {
      if (p < TT) {                    // layer 0, step p
        float gi = Gbuf[eb * 129 +      eu];
        float gf = Gbuf[eb * 129 + 16 + eu];
        float gg = Gbuf[eb * 129 + 32 + eu];
        float go = Gbuf[eb * 129 + 48 + eu];
        float iv = sigm(gi), fv = sigm(gf), gv = tanh_(gg), ov = sigm(go);
        c0 = fv * c0 + iv * gv;
        float h = ov * tanh_(c0);
        *((_Float16*)(h0g + wrpar * 131072) +
          (size_t)(g*QB + eb) * HH + (w*16 + eu)) = (_Float16)h;
      }
      if (p >= 1) {                    // layer 1, step p-1
        float gi = Gbuf[eb * 129 + 64 +  eu];
        float gf = Gbuf[eb * 129 + 80 +  eu];
        float gg = Gbuf[eb * 129 + 96 +  eu];
        float go = Gbuf[eb * 129 + 112 + eu];
        float iv = sigm(gi), fv = sigm(gf), gv = tanh_(gg), ov = sigm(go);
        c1 = fv * c1 + iv * gv;
        float h = ov * tanh_(c1);
        if (p < TT) {
          *((_Float16*)(h1g + wrpar * 131072) +
            (size_t)(g*QB + eb) * HH + (w*16 + eu)) = (_Float16)h;
        } else {                       // final step: fp32 output
          out[(size_t)(g*QB + eb) * HH + (w*16 + eu)] = h;
        }
      }
    }

    // ---- inter-wg barrier within batch group (agent scope, monotone flags) ----
    if (p < TT) {
      __syncthreads();   // drains each thread's vmcnt -> all h writes are in L2
      if (tid == 0)
        __hip_atomic_store(&flags[g * WPG + w], (unsigned)(p + 1),
                           __ATOMIC_RELEASE, __HIP_MEMORY_SCOPE_AGENT);
      if (tid < WPG) {
        while (__hip_atomic_load(&flags[g * WPG + tid],
                                 __ATOMIC_RELAXED, __HIP_MEMORY_SCOPE_AGENT)
               < (unsigned)(p + 1)) {}
        (void)__hip_atomic_load(&flags[g * WPG + tid],
                                __ATOMIC_ACQUIRE, __HIP_MEMORY_SCOPE_AGENT);
      }
      __syncthreads();
    }
  }
}

extern "C" void kernel_launch(void* const* d_in, const int* in_sizes, int n_in,
                              void* d_out, int out_size, void* d_ws, size_t ws_size,
                              hipStream_t stream) {
  (void)in_sizes; (void)n_in; (void)out_size;
  if (ws_size < 524800) return;   // need 512KB h buffers + flags

  const float* M    = (const float*)d_in[0];
  const float* Wih0 = (const float*)d_in[1];
  const float* Whh0 = (const float*)d_in[2];
  const float* bih0 = (const float*)d_in[3];
  const float* bhh0 = (const float*)d_in[4];
  const float* Wih1 = (const float*)d_in[5];
  const float* Whh1 = (const float*)d_in[6];
  const float* bih1 = (const float*)d_in[7];
  const float* bhh1 = (const float*)d_in[8];

  const int nz = 32800;            // 524800 B / 16
  zero_ws<<<(nz + 255) / 256, 256, 0, stream>>>((uint4*)d_ws, nz);
  lstm_kernel<<<GROUPS * WPG, NTH, 0, stream>>>(M, Wih0, Whh0, bih0, bhh0,
                                                Wih1, Whh1, bih1, bhh1,
                                                (float*)d_out, (char*)d_ws);
}

// Round 2
// 1837.259 us; speedup vs baseline: 2.0068x; 2.0068x over previous
//
#include <hip/hip_runtime.h>
#include <hip/hip_fp16.h>

// 2-layer LSTM, B=256 T=512 I=32 H=256.
// 8 batch-groups x 16 wgs; weights register-resident (fp16 MFMA fragments).
// Cross-wg h exchange + flags via sc0/sc1 (L2-bypass, Infinity-Cache-coherent)
// fine-grained stores/loads -- no buffer_wbl2 / buffer_inv L2 flushes.
// h global layout blocked per-wg: [par][g][w][32b][16u] fp16 (1KB/wg contiguous).

#define GROUPS 8
#define WPG    16
#define NTH    512
#define QB     32
#define HH     256
#define TT     512
#define II     32

typedef _Float16 f16x8 __attribute__((ext_vector_type(8)));
typedef float    f32x4 __attribute__((ext_vector_type(4)));

__device__ __forceinline__ f16x8 cvt8(const float* p) {
  const float4 a = *(const float4*)p;
  const float4 b = *(const float4*)(p + 4);
  f16x8 r;
  r[0]=(_Float16)a.x; r[1]=(_Float16)a.y; r[2]=(_Float16)a.z; r[3]=(_Float16)a.w;
  r[4]=(_Float16)b.x; r[5]=(_Float16)b.y; r[6]=(_Float16)b.z; r[7]=(_Float16)b.w;
  return r;
}

__device__ __forceinline__ float sigm(float x){ return 1.f/(1.f + __expf(-x)); }
__device__ __forceinline__ float tanh_(float x){ return 1.f - 2.f/(1.f + __expf(2.f*x)); }

// ---- L3-coherent (L2-bypassing) access primitives ----
__device__ __forceinline__ uint4 load16_sc(const void* p) {
  uint4 r;
  asm volatile("global_load_dwordx4 %0, %1, off sc0 sc1"
               : "=v"(r) : "v"(p) : "memory");
  return r;
}
__device__ __forceinline__ void store2_sc(void* p, unsigned v) {
  asm volatile("global_store_short %0, %1, off sc0 sc1"
               :: "v"(p), "v"(v) : "memory");
}
__device__ __forceinline__ void storeflag_sc(void* p, unsigned v) {
  asm volatile("global_store_dword %0, %1, off sc0 sc1"
               :: "v"(p), "v"(v) : "memory");
}
__device__ __forceinline__ unsigned loadflag_sc(const void* p) {
  unsigned r;
  asm volatile("global_load_dword %0, %1, off sc0 sc1\n\ts_waitcnt vmcnt(0)"
               : "=v"(r) : "v"(p) : "memory");
  return r;
}

__global__ void zero_ws(uint4* p, int n) {
  int i = blockIdx.x * blockDim.x + threadIdx.x;
  if (i < n) p[i] = make_uint4(0u,0u,0u,0u);
}

__global__ __launch_bounds__(NTH, 2) void lstm_kernel(
    const float* __restrict__ M,
    const float* __restrict__ Wih0, const float* __restrict__ Whh0,
    const float* __restrict__ bih0, const float* __restrict__ bhh0,
    const float* __restrict__ Wih1, const float* __restrict__ Whh1,
    const float* __restrict__ bih1, const float* __restrict__ bhh1,
    float* __restrict__ out, char* __restrict__ ws)
{
  __shared__ float Gbuf[QB * 129];              // gate pre-activations [32][128] pad->129
  __shared__ __align__(16) char h0l[QB * 512];  // h0[p-1] staged, fp16, XOR-swizzled
  __shared__ __align__(16) char h1l[QB * 512];  // h1[p-2] staged

  const int tid  = threadIdx.x;
  const int lane = tid & 63;
  const int wv   = tid >> 6;           // 0..7
  const int g    = blockIdx.x & 7;     // batch group (XCD locality heuristic)
  const int w    = blockIdx.x >> 3;    // 0..15 wg within group

  char* h0g = ws;                      // [2 par][8 g][16 w][32 b][16 u] fp16 = 262144 B
  char* h1g = ws + 262144;
  unsigned* flags = (unsigned*)(ws + 524288);   // [8][16] monotone phase counters

  const int col16 = lane & 15;
  const int ko8   = (lane >> 4) << 3;  // k-offset in elements (0,8,16,24)
  const int q     = wv & 3;            // gate: 0=i 1=f 2=g 3=o
  const bool isL1 = wv >= 4;
  const int grow  = q * HH + w * 16 + col16;    // global weight row (gate col)

  // ---- weight fragments -> registers (loaded once) ----
  const float* WA = isL1 ? Wih1 : Whh0;
  f16x8 BA[8], BB[8], Bi0;
  #pragma unroll
  for (int kt = 0; kt < 8; ++kt)
    BA[kt] = cvt8(WA + (size_t)grow * HH + kt * 32 + ko8);
  if (isL1) {
    #pragma unroll
    for (int kt = 0; kt < 8; ++kt)
      BB[kt] = cvt8(Whh1 + (size_t)grow * HH + kt * 32 + ko8);
  } else {
    Bi0 = cvt8(Wih0 + grow * II + ko8);
  }
  const float bias = isL1 ? (bih1[grow] + bhh1[grow]) : (bih0[grow] + bhh0[grow]);

  // elementwise ownership: thread -> (batch, unit), unit fastest (coalesced h stores)
  const int eb = tid >> 4;             // 0..31
  const int eu = tid & 15;             // 0..15
  float c0 = 0.f, c1 = 0.f;

  for (int p = 0; p <= TT; ++p) {
    const int rdpar = (p + 1) & 1;
    const int wrpar = p & 1;

    // ---- stage this group's h0[p-1], h1[p-2] (16KB each, contiguous) into LDS ----
    {
      const char* s0 = h0g + rdpar * 131072 + (g << 14);
      const char* s1 = h1g + rdpar * 131072 + (g << 14);
      uint4 vv[4];
      #pragma unroll
      for (int pass = 0; pass < 4; ++pass) {
        int c  = tid + pass * NTH;           // 0..2047
        int bi = c >> 10;                    // 0: h0, 1: h1
        int cc = c & 1023;                   // 16B chunk within group's 16KB
        vv[pass] = load16_sc((bi ? s1 : s0) + (cc << 4));
      }
      asm volatile("s_waitcnt vmcnt(0)" ::: "memory");
      __builtin_amdgcn_sched_barrier(0);
      #pragma unroll
      for (int pass = 0; pass < 4; ++pass) {
        int c  = tid + pass * NTH;
        int bi = c >> 10;
        int cc = c & 1023;
        int wq = cc >> 6;                    // source wg 0..15
        int b  = (cc >> 1) & 31;             // batch row
        int colb = (wq << 5) + ((cc & 1) << 4);   // byte col in [32][512B] tile
        *(uint4*)((bi ? h1l : h0l) +
                  ((b << 9) + (colb ^ ((b & 7) << 4)))) = vv[pass];
      }
    }
    __syncthreads();

    // ---- MFMA: gates[32 x 16cols] for this wave's gate-column slice ----
    {
      f32x4 a0 = {bias, bias, bias, bias};
      f32x4 a1 = a0;
      const bool active = isL1 ? (p >= 1) : (p < TT);
      if (active) {
        if (!isL1) {
          const float* m0 = M + (((size_t)(g*QB + col16     ) * TT + p) * II + ko8);
          const float* m1 = M + (((size_t)(g*QB + 16 + col16) * TT + p) * II + ko8);
          f16x8 am0 = cvt8(m0), am1 = cvt8(m1);
          a0 = __builtin_amdgcn_mfma_f32_16x16x32_f16(am0, Bi0, a0, 0, 0, 0);
          a1 = __builtin_amdgcn_mfma_f32_16x16x32_f16(am1, Bi0, a1, 0, 0, 0);
        }
        #pragma unroll
        for (int kt = 0; kt < 8; ++kt) {
          int r0 = col16, r1 = 16 + col16;
          int kb = (kt << 6) + ((lane >> 4) << 4);
          f16x8 x0 = *(const f16x8*)(h0l + ((r0 << 9) + (kb ^ ((r0 & 7) << 4))));
          f16x8 x1 = *(const f16x8*)(h0l + ((r1 << 9) + (kb ^ ((r1 & 7) << 4))));
          a0 = __builtin_amdgcn_mfma_f32_16x16x32_f16(x0, BA[kt], a0, 0, 0, 0);
          a1 = __builtin_amdgcn_mfma_f32_16x16x32_f16(x1, BA[kt], a1, 0, 0, 0);
        }
        if (isL1) {
          #pragma unroll
          for (int kt = 0; kt < 8; ++kt) {
            int r0 = col16, r1 = 16 + col16;
            int kb = (kt << 6) + ((lane >> 4) << 4);
            f16x8 y0 = *(const f16x8*)(h1l + ((r0 << 9) + (kb ^ ((r0 & 7) << 4))));
            f16x8 y1 = *(const f16x8*)(h1l + ((r1 << 9) + (kb ^ ((r1 & 7) << 4))));
            a0 = __builtin_amdgcn_mfma_f32_16x16x32_f16(y0, BB[kt], a0, 0, 0, 0);
            a1 = __builtin_amdgcn_mfma_f32_16x16x32_f16(y1, BB[kt], a1, 0, 0, 0);
          }
        }
      }
      const int colL = (wv << 4) + col16;
      const int r0 = (lane >> 4) << 2;
      #pragma unroll
      for (int r = 0; r < 4; ++r) {
        Gbuf[(r0 + r) * 129 + colL]      = a0[r];
        Gbuf[(r0 + r + 16) * 129 + colL] = a1[r];
      }
    }
    __syncthreads();

    // ---- elementwise gate nonlinearity + state update, coalesced sc1 h stores ----
    {
      const int hoff = ((g * WPG + w) << 10) + ((eb * 16 + eu) << 1);  // bytes
      if (p < TT) {                    // layer 0, step p
        float gi = Gbuf[eb * 129 +      eu];
        float gf = Gbuf[eb * 129 + 16 + eu];
        float gg = Gbuf[eb * 129 + 32 + eu];
        float go = Gbuf[eb * 129 + 48 + eu];
        float iv = sigm(gi), fv = sigm(gf), gv = tanh_(gg), ov = sigm(go);
        c0 = fv * c0 + iv * gv;
        float h = ov * tanh_(c0);
        unsigned short hb = __builtin_bit_cast(unsigned short, (_Float16)h);
        store2_sc(h0g + wrpar * 131072 + hoff, (unsigned)hb);
      }
      if (p >= 1) {                    // layer 1, step p-1
        float gi = Gbuf[eb * 129 + 64 +  eu];
        float gf = Gbuf[eb * 129 + 80 +  eu];
        float gg = Gbuf[eb * 129 + 96 +  eu];
        float go = Gbuf[eb * 129 + 112 + eu];
        float iv = sigm(gi), fv = sigm(gf), gv = tanh_(gg), ov = sigm(go);
        c1 = fv * c1 + iv * gv;
        float h = ov * tanh_(c1);
        if (p < TT) {
          unsigned short hb = __builtin_bit_cast(unsigned short, (_Float16)h);
          store2_sc(h1g + wrpar * 131072 + hoff, (unsigned)hb);
        } else {                       // final step: fp32 output (normal store)
          out[(size_t)(g*QB + eb) * HH + (w*16 + eu)] = h;
        }
      }
    }

    // ---- inter-wg barrier within batch group (fine-grained sc1 flags) ----
    if (p < TT) {
      __syncthreads();   // per-thread vmcnt(0) drain -> all h stores at L3
      if (tid == 0)
        storeflag_sc(flags + g * WPG + w, (unsigned)(p + 1));
      if (tid < WPG) {
        while (loadflag_sc(flags + g * WPG + tid) < (unsigned)(p + 1)) {}
      }
      __syncthreads();
    }
  }
}

extern "C" void kernel_launch(void* const* d_in, const int* in_sizes, int n_in,
                              void* d_out, int out_size, void* d_ws, size_t ws_size,
                              hipStream_t stream) {
  (void)in_sizes; (void)n_in; (void)out_size;
  if (ws_size < 524800) return;   // 512KB h buffers + flags

  const float* M    = (const float*)d_in[0];
  const float* Wih0 = (const float*)d_in[1];
  const float* Whh0 = (const float*)d_in[2];
  const float* bih0 = (const float*)d_in[3];
  const float* bhh0 = (const float*)d_in[4];
  const float* Wih1 = (const float*)d_in[5];
  const float* Whh1 = (const float*)d_in[6];
  const float* bih1 = (const float*)d_in[7];
  const float* bhh1 = (const float*)d_in[8];

  const int nz = 32800;            // 524800 B / 16
  zero_ws<<<(nz + 255) / 256, 256, 0, stream>>>((uint4*)d_ws, nz);
  lstm_kernel<<<GROUPS * WPG, NTH, 0, stream>>>(M, Wih0, Whh0, bih0, bhh0,
                                                Wih1, Whh1, bih1, bhh1,
                                                (float*)d_out, (char*)d_ws);
}